// Round 1
// baseline (198.130 us; speedup 1.0000x reference)
//
#include <hip/hip_runtime.h>
#include <float.h>

#define K_NN 10
#define BATCH 8
#define CIN 6
#define NPTS 4096
#define COUT 64
#define NSEG 8
#define SEGLEN (NPTS / NSEG)    // 512
#define CHUNK 16
#define NCHUNK (SEGLEN / CHUNK) // 32
#define NWORD (SEGLEN / 32)     // 16
#define NEG_SLOPE 0.2f
#define BN_EPS 1e-5f

// ---- workspace layout (bytes) ----
// part[] aliases q[]: part is fully consumed by merge_kernel before feat_kernel writes q.
static constexpr size_t OFF_IDX = 0;                                                   // int[8*10*4096]  (plane layout [b][j][n])
static constexpr size_t OFF_PTS = OFF_IDX + (size_t)BATCH * K_NN * NPTS * sizeof(int); // float4[8*4096]
static constexpr size_t OFF_Q   = OFF_PTS + (size_t)BATCH * NPTS * sizeof(float4);     // alias: q / part
static constexpr size_t SZ_Q    = (size_t)NSEG * BATCH * NPTS * K_NN * sizeof(int);    // 10.49 MB
static constexpr size_t OFF_ST  = OFF_Q + SZ_Q;                                        // double[27]
static constexpr size_t OFF_SS  = OFF_ST + 32 * sizeof(double);                        // float[128]

__device__ __forceinline__ float wave_sum(float v) {
#pragma unroll
    for (int m = 32; m >= 1; m >>= 1) v += __shfl_xor(v, m, 64);
    return v;
}
__device__ __forceinline__ float wave_max(float v) {
#pragma unroll
    for (int m = 32; m >= 1; m >>= 1) v = fmaxf(v, __shfl_xor(v, m, 64));
    return v;
}

// pts stores (2x, 2y, 2z, ||p||^2); query coords pre-halved once per thread.
// d' = 2*inner - ||c||^2  == fma(2cx,qx/1, ...) -> exactly 3 FMAs (neg modifier on c.w free).
// Monotone shift of true distance, used consistently in knn_part/drain/merge.
__device__ __forceinline__ float distp(float qx, float qy, float qz, float4 c) {
    return fmaf(c.x, qx, fmaf(c.y, qy, fmaf(c.z, qz, -c.w)));
}

__device__ __forceinline__ float fmax3(float a, float b, float c) {
    return fmaxf(fmaxf(a, b), c);   // fuses to v_max3_f32 (exact for non-NaN)
}

// ---- Kernel P: pack (2x,2y,2z,||p||^2) per point; block 0 zeroes stats ----
__global__ __launch_bounds__(256) void prep_pts(const float* __restrict__ x,
                                                float4* __restrict__ pts,
                                                double* __restrict__ stats) {
    if (blockIdx.x == 0 && threadIdx.x < 27) stats[threadIdx.x] = 0.0;
    int t = blockIdx.x * 256 + threadIdx.x;   // 0..32767
    int b = t >> 12;
    int n = t & (NPTS - 1);
    const float* xb = x + (size_t)b * CIN * NPTS;
    float x0 = xb[n];
    float x1 = xb[NPTS + n];
    float x2 = xb[2 * NPTS + n];
    pts[t] = make_float4(2.0f * x0, 2.0f * x1, 2.0f * x2, x0 * x0 + x1 * x1 + x2 * x2);
}

// ---- Kernel A1: per-segment exact top-10 ----
// Phase 1: chunk maxima (chunks of 16, v_max3 tree) through a 10-deep branchless
//          chain -> thr = 10th-largest chunk max. Provably thr <= v10_seg (10
//          distinct chunks each contain >=1 element >= thr).
// Phase 2: per-lane 32-bit survivor BITMASK per 32-point word:
//          mask = (mask<<1) | (d >= thr).  No LDS, no counter, no overflow: exact.
// Drain:   clz-iterate set bits MSB-first (== ascending m: R1 tie semantics),
//          strict-> insertion over survivors.
__global__ __launch_bounds__(256) void knn_part(const float4* __restrict__ pts,
                                                int* __restrict__ part) {
    int b = blockIdx.y;
    int s = blockIdx.z;
    int n = blockIdx.x * 256 + threadIdx.x;
    const float4* p = pts + (size_t)b * NPTS;   // wave-uniform base -> scalar loads
    float4 q4 = p[n];
    float qx = 0.5f * q4.x, qy = 0.5f * q4.y, qz = 0.5f * q4.z;

    int m0 = s * SEGLEN;

    // ---- phase 1: threshold from chunk maxima ----
    float vals[K_NN];
#pragma unroll
    for (int j = 0; j < K_NN; j++) vals[j] = -FLT_MAX;

    for (int ch = 0; ch < NCHUNK; ch++) {
        const float4* cp = p + (m0 + ch * CHUNK);
        float d[CHUNK];
#pragma unroll
        for (int u = 0; u < CHUNK; u++) d[u] = distp(qx, qy, qz, cp[u]);
        float a0 = fmax3(d[0], d[1], d[2]);
        float a1 = fmax3(d[3], d[4], d[5]);
        float a2 = fmax3(d[6], d[7], d[8]);
        float a3 = fmax3(d[9], d[10], d[11]);
        float a4 = fmax3(d[12], d[13], d[14]);
        float t = fmaxf(fmax3(fmax3(a0, a1, a2), a3, a4), d[15]);
#pragma unroll
        for (int j = 0; j < K_NN; j++) {
            float hi = fmaxf(vals[j], t);
            t = fminf(vals[j], t);
            vals[j] = hi;
        }
    }
    float thr = vals[K_NN - 1];   // 10th-largest chunk max  (<= exact v10_seg)

    // ---- phase 2 + drain: bitmask survivors, exact strict-> insert ----
    float fv[K_NN];
    int fi[K_NN];
#pragma unroll
    for (int j = 0; j < K_NN; j++) { fv[j] = -FLT_MAX; fi[j] = 0; }

    for (int w = 0; w < NWORD; w++) {
        const float4* cp = p + (m0 + w * 32);
        unsigned int mask = 0u;
#pragma unroll
        for (int u = 0; u < 32; u++) {
            float d = distp(qx, qy, qz, cp[u]);
            mask = (mask << 1) | (d >= thr ? 1u : 0u);   // point u -> bit (31-u)
        }
        int base = m0 + w * 32;
        while (mask) {
            int j = __builtin_clz(mask);        // MSB-first == ascending m
            mask ^= (0x80000000u >> j);
            int m = base + j;
            float4 c = p[m];                    // L1-hot (segment = 8 KB)
            float d = distp(qx, qy, qz, c);
            if (d > fv[K_NN - 1]) {
                fv[K_NN - 1] = d;
                fi[K_NN - 1] = m;
#pragma unroll
                for (int t2 = K_NN - 1; t2 > 0; t2--) {
                    if (fv[t2] > fv[t2 - 1]) {
                        float tv = fv[t2]; fv[t2] = fv[t2 - 1]; fv[t2 - 1] = tv;
                        int ti = fi[t2]; fi[t2] = fi[t2 - 1]; fi[t2 - 1] = ti;
                    }
                }
            }
        }
    }

    int* o = part + (((size_t)s * BATCH + b) * K_NN) * NPTS + n;
#pragma unroll
    for (int j = 0; j < K_NN; j++) o[(size_t)j * NPTS] = fi[j];
}

// ---- Kernel A2: merge 8 segment lists -> global top-10 (re-evaluates 80 cands) ----
// 64-thr blocks x 512: fills all 256 CUs (was 128 blocks = half chip idle).
__global__ __launch_bounds__(64) void merge_kernel(const float4* __restrict__ pts,
                                                   const int* __restrict__ part,
                                                   int* __restrict__ idxo) {
    int b = blockIdx.y;
    int n = blockIdx.x * 64 + threadIdx.x;
    const float4* p = pts + (size_t)b * NPTS;
    float4 q4 = p[n];
    float qx = 0.5f * q4.x, qy = 0.5f * q4.y, qz = 0.5f * q4.z;

    float vals[K_NN];
    int inds[K_NN];
#pragma unroll
    for (int j = 0; j < K_NN; j++) { vals[j] = -FLT_MAX; inds[j] = 0; }

#pragma unroll
    for (int s = 0; s < NSEG; s++) {
        const int* pp = part + (((size_t)s * BATCH + b) * K_NN) * NPTS + n;
#pragma unroll
        for (int j = 0; j < K_NN; j++) {
            int m = pp[(size_t)j * NPTS];
            float4 c = p[m];                     // divergent but L1/L2-resident
            float d = distp(qx, qy, qz, c);
            if (d > vals[K_NN - 1]) {
                vals[K_NN - 1] = d;
                inds[K_NN - 1] = m;
#pragma unroll
                for (int t = K_NN - 1; t > 0; t--) {
                    if (vals[t] > vals[t - 1]) {
                        float tv = vals[t]; vals[t] = vals[t - 1]; vals[t - 1] = tv;
                        int ti = inds[t]; inds[t] = inds[t - 1]; inds[t - 1] = ti;
                    }
                }
            }
        }
    }

    // plane layout [b][j][n] : coalesced write, coalesced read in feat
    int* o = idxo + (size_t)b * K_NN * NPTS + n;
#pragma unroll
    for (int j = 0; j < K_NN; j++) o[(size_t)j * NPTS] = inds[j];
}

// ---- Kernel B: gather + center + q[b,o,n] = max_k (W feat) + moment stats ----
// 128-thr blocks x 256: 1 block/CU on all CUs (was 128 blocks = half chip idle).
// pts xyz are pre-doubled: un-double at gather (3 muls) so centering/stats
// arithmetic stays bit-identical to the verified version.
__global__ __launch_bounds__(128) void feat_kernel(const float4* __restrict__ pts,
                                                   const float* __restrict__ x,
                                                   const float* __restrict__ W,
                                                   const int* __restrict__ idx,
                                                   float* __restrict__ q,
                                                   double* __restrict__ stats) {
    __shared__ float sW[COUT * CIN];
    __shared__ float sred[2][27];
    for (int i = threadIdx.x; i < COUT * CIN; i += 128) sW[i] = W[i];
    __syncthreads();

    int b = blockIdx.y;
    int n = blockIdx.x * 128 + threadIdx.x;
    const float* xb = x + (size_t)b * CIN * NPTS;
    const float4* p = pts + (size_t)b * NPTS;

    int nb[K_NN];
#pragma unroll
    for (int k = 0; k < K_NN; k++) nb[k] = idx[((size_t)b * K_NN + k) * NPTS + n];

    float f[CIN][K_NN];
#pragma unroll
    for (int k = 0; k < K_NN; k++) {
        float4 c = p[nb[k]];                    // xyz in one 16B gather (doubled)
        f[0][k] = 0.5f * c.x; f[1][k] = 0.5f * c.y; f[2][k] = 0.5f * c.z;
    }
#pragma unroll
    for (int c = 3; c < CIN; c++)
#pragma unroll
        for (int k = 0; k < K_NN; k++)
            f[c][k] = xb[c * NPTS + nb[k]];

    // center xyz over k, scale by 10
#pragma unroll
    for (int c = 0; c < 3; c++) {
        float s = 0.f;
#pragma unroll
        for (int k = 0; k < K_NN; k++) s += f[c][k];
        float m = s / 10.0f;
#pragma unroll
        for (int k = 0; k < K_NN; k++) f[c][k] = (f[c][k] - m) * 10.0f;
    }

    // q[b,o,n] = max_k y (BN affine + leaky are monotone -> applied in reduce)
    float* qb = q + (size_t)b * COUT * NPTS + n;
#pragma unroll
    for (int o = 0; o < COUT; o++) {
        float w0 = sW[o * 6 + 0], w1 = sW[o * 6 + 1], w2 = sW[o * 6 + 2];
        float w3 = sW[o * 6 + 3], w4 = sW[o * 6 + 4], w5 = sW[o * 6 + 5];
        float mx = -FLT_MAX;
#pragma unroll
        for (int k = 0; k < K_NN; k++) {
            float y = w0 * f[0][k] + w1 * f[1][k] + w2 * f[2][k] +
                      w3 * f[3][k] + w4 * f[4][k] + w5 * f[5][k];
            mx = fmaxf(mx, y);
        }
        qb[(size_t)o * NPTS] = mx;
    }

    // moment stats: S1[6], S2[21]
    float s1[CIN];
#pragma unroll
    for (int c = 0; c < CIN; c++) {
        float s = 0.f;
#pragma unroll
        for (int k = 0; k < K_NN; k++) s += f[c][k];
        s1[c] = s;
    }
    float s2[21];
#pragma unroll
    for (int i = 0; i < 21; i++) s2[i] = 0.f;
#pragma unroll
    for (int k = 0; k < K_NN; k++) {
        int pp = 0;
#pragma unroll
        for (int c = 0; c < CIN; c++)
#pragma unroll
            for (int c2 = c; c2 < CIN; c2++) {
                s2[pp] += f[c][k] * f[c2][k];
                pp++;
            }
    }
#pragma unroll
    for (int c = 0; c < CIN; c++) s1[c] = wave_sum(s1[c]);
#pragma unroll
    for (int i = 0; i < 21; i++) s2[i] = wave_sum(s2[i]);

    int wv = threadIdx.x >> 6;
    int ln = threadIdx.x & 63;
    if (ln == 0) {
#pragma unroll
        for (int c = 0; c < CIN; c++) sred[wv][c] = s1[c];
#pragma unroll
        for (int i = 0; i < 21; i++) sred[wv][6 + i] = s2[i];
    }
    __syncthreads();
    if (threadIdx.x < 27) {
        float t = sred[0][threadIdx.x] + sred[1][threadIdx.x];
        atomicAdd(&stats[threadIdx.x], (double)t);
    }
}

// ---- Kernel B2: fold moments through W -> per-channel scale/shift ----
__global__ void stats_kernel(const double* __restrict__ stats,
                             const float* __restrict__ W,
                             const float* __restrict__ gamma,
                             const float* __restrict__ beta,
                             float* __restrict__ ss) {
    int o = threadIdx.x;  // 64 threads
    const double minv = 1.0 / (double)((size_t)BATCH * NPTS * K_NN);
    double w[CIN];
#pragma unroll
    for (int c = 0; c < CIN; c++) w[c] = (double)W[o * CIN + c];
    double mu = 0.0;
#pragma unroll
    for (int c = 0; c < CIN; c++) mu += w[c] * stats[c];
    mu *= minv;
    double ey2 = 0.0;
    int p = 6;
#pragma unroll
    for (int c = 0; c < CIN; c++)
#pragma unroll
        for (int c2 = c; c2 < CIN; c2++) {
            double v = w[c] * w[c2] * stats[p];
            ey2 += (c2 == c) ? v : 2.0 * v;
            p++;
        }
    ey2 *= minv;
    double var = ey2 - mu * mu;
    float scale = gamma[o] * rsqrtf((float)var + BN_EPS);
    float shift = beta[o] - (float)mu * scale;
    ss[o] = scale;
    ss[COUT + o] = shift;
}

// ---- Kernel C: z = leaky(scale*q+shift); reduce max & mean over n ----
__global__ __launch_bounds__(256) void reduce_kernel(const float* __restrict__ q,
                                                     const float* __restrict__ ss,
                                                     float* __restrict__ out) {
    int o = blockIdx.x;
    int b = blockIdx.y;
    const float* qp = q + ((size_t)b * COUT + o) * NPTS;
    float scale = ss[o], shift = ss[COUT + o];
    float mx = -FLT_MAX, sm = 0.f;
    for (int i = threadIdx.x; i < NPTS; i += 256) {
        float z = scale * qp[i] + shift;
        z = (z >= 0.f) ? z : NEG_SLOPE * z;
        mx = fmaxf(mx, z);
        sm += z;
    }
    mx = wave_max(mx);
    sm = wave_sum(sm);
    __shared__ float smx[4], ssm2[4];
    int wv = threadIdx.x >> 6;
    int ln = threadIdx.x & 63;
    if (ln == 0) { smx[wv] = mx; ssm2[wv] = sm; }
    __syncthreads();
    if (threadIdx.x == 0) {
        float m = fmaxf(fmaxf(smx[0], smx[1]), fmaxf(smx[2], smx[3]));
        float s = ssm2[0] + ssm2[1] + ssm2[2] + ssm2[3];
        out[b * 2 * COUT + o] = m;
        out[b * 2 * COUT + COUT + o] = s * (1.0f / (float)NPTS);
    }
}

extern "C" void kernel_launch(void* const* d_in, const int* in_sizes, int n_in,
                              void* d_out, int out_size, void* d_ws, size_t ws_size,
                              hipStream_t stream) {
    const float* x     = (const float*)d_in[0];
    const float* W     = (const float*)d_in[1];
    const float* gamma = (const float*)d_in[2];
    const float* beta  = (const float*)d_in[3];
    float* out = (float*)d_out;

    char* ws = (char*)d_ws;
    int*    idx   = (int*)(ws + OFF_IDX);
    float4* pts   = (float4*)(ws + OFF_PTS);
    int*    part  = (int*)(ws + OFF_Q);     // aliases q region (consumed before q written)
    float*  q     = (float*)(ws + OFF_Q);
    double* stats = (double*)(ws + OFF_ST);
    float*  ss    = (float*)(ws + OFF_SS);

    prep_pts<<<BATCH * NPTS / 256, 256, 0, stream>>>(x, pts, stats);
    knn_part<<<dim3(NPTS / 256, BATCH, NSEG), 256, 0, stream>>>(pts, part);
    merge_kernel<<<dim3(NPTS / 64, BATCH), 64, 0, stream>>>(pts, part, idx);
    feat_kernel<<<dim3(NPTS / 128, BATCH), 128, 0, stream>>>(pts, x, W, idx, q, stats);
    stats_kernel<<<1, COUT, 0, stream>>>(stats, W, gamma, beta, ss);
    reduce_kernel<<<dim3(COUT, BATCH), 256, 0, stream>>>(q, ss, out);
}